// Round 3
// baseline (52.416 us; speedup 1.0000x reference)
//
#include <hip/hip_runtime.h>
#include <hip/hip_bf16.h>

#define N_ROWS 262144
#define DIM    64
#define KCB    512

#define BLOCKS  512
#define THREADS 1024         // 16 waves; 32 rows per wave; 512 rows per block

typedef __bf16 bf16x8 __attribute__((ext_vector_type(8)));
typedef float  f32x4  __attribute__((ext_vector_type(4)));

__device__ inline float dot4(float4 a) {
    return a.x * a.x + a.y * a.y + a.z * a.z + a.w * a.w;
}

// ---- kernel 1: stage+wnorm, argmin, coalesced gather-store, loss -----------
__global__ __launch_bounds__(THREADS, 8) void vq_main(
    const float* __restrict__ x, const float* __restrict__ cb,
    float* __restrict__ out, float* __restrict__ partials)
{
    // negated codebook as bf16 granules, XOR-swizzled (measured 0 conflicts)
    __shared__ bf16x8 cb_sh[KCB * 8];      // 64 KiB
    __shared__ f32x4  wn_sh4[KCB / 4];     // 2 KiB (wn[k] = 1 + 0.5||w_k||^2)
    __shared__ float  red_sh[16];

    const int tid    = threadIdx.x;
    const int lane   = tid & 63;
    const int wave   = tid >> 6;
    const int lane15 = lane & 15;
    const int half   = lane >> 4;          // 0..3

    // ---- stage NEGATED codebook f32 -> bf16 into LDS; fold in wn compute ----
    // 8 consecutive lanes hold the 8 granules of one codeword row.
    #pragma unroll
    for (int it = 0; it < (KCB * 8) / THREADS; ++it) {
        const int fg = tid + it * THREADS;
        const int row = fg >> 3, g = fg & 7;
        const float* src = cb + row * DIM + g * 8;
        float4 f0 = *(const float4*)src;
        float4 f1 = *(const float4*)(src + 4);
        float sq = dot4(f0) + dot4(f1);
        sq += __shfl_xor(sq, 1);
        sq += __shfl_xor(sq, 2);
        sq += __shfl_xor(sq, 4);
        bf16x8 v;
        v[0] = (__bf16)(-f0.x); v[1] = (__bf16)(-f0.y); v[2] = (__bf16)(-f0.z); v[3] = (__bf16)(-f0.w);
        v[4] = (__bf16)(-f1.x); v[5] = (__bf16)(-f1.y); v[6] = (__bf16)(-f1.z); v[7] = (__bf16)(-f1.w);
        cb_sh[row * 8 + (g ^ (row & 7))] = v;
        if (g == 0) ((float*)wn_sh4)[row] = 1.0f + 0.5f * sq;
    }

    // ---- load x for 32 rows/wave (2 cols of 16), build B frags + ||x||^2 ----
    const int wrow = blockIdx.x * 512 + wave * 32;
    bf16x8 blo[2], bhi[2];
    float  xn[2];
    #pragma unroll
    for (int c = 0; c < 2; ++c) {
        const float* xr = x + (size_t)(wrow + c * 16 + lane15) * DIM + half * 8;
        float4 f0 = *(const float4*)xr;
        float4 f1 = *(const float4*)(xr + 4);
        float4 f2 = *(const float4*)(xr + 32);
        float4 f3 = *(const float4*)(xr + 36);
        xn[c] = dot4(f0) + dot4(f1) + dot4(f2) + dot4(f3);
        bf16x8 lo, hi;
        lo[0] = (__bf16)f0.x; lo[1] = (__bf16)f0.y; lo[2] = (__bf16)f0.z; lo[3] = (__bf16)f0.w;
        lo[4] = (__bf16)f1.x; lo[5] = (__bf16)f1.y; lo[6] = (__bf16)f1.z; lo[7] = (__bf16)f1.w;
        hi[0] = (__bf16)f2.x; hi[1] = (__bf16)f2.y; hi[2] = (__bf16)f2.z; hi[3] = (__bf16)f2.w;
        hi[4] = (__bf16)f3.x; hi[5] = (__bf16)f3.y; hi[6] = (__bf16)f3.z; hi[7] = (__bf16)f3.w;
        blo[c] = lo; bhi[c] = hi;
    }
    __syncthreads();

    const int swz_lo = half ^ (lane & 7);
    const int swz_hi = (4 + half) ^ (lane & 7);
    const unsigned halfbits = (unsigned)(half * 4);

    // packed (score | k) running minima, one per col
    unsigned u0 = 0xFFFFFFFFu, u1 = 0xFFFFFFFFu;

    #pragma unroll 8
    for (int t = 0; t < 32; ++t) {
        const int arow = t * 16 + lane15;
        bf16x8 alo = cb_sh[arow * 8 + swz_lo];
        bf16x8 ahi = cb_sh[arow * 8 + swz_hi];
        f32x4  wnv = wn_sh4[t * 4 + half];
        unsigned* us[2] = {&u0, &u1};
        #pragma unroll
        for (int c = 0; c < 2; ++c) {
            // C-init = wn, A = -w  ->  acc[r] = wn[k] - x.w  (the score)
            f32x4 acc = wnv;
            acc = __builtin_amdgcn_mfma_f32_16x16x32_bf16(alo, blo[c], acc, 0, 0, 0);
            acc = __builtin_amdgcn_mfma_f32_16x16x32_bf16(ahi, bhi[c], acc, 0, 0, 0);
            unsigned p0 = (__float_as_uint(acc[0]) & 0xFFFFFE00u) | (unsigned)(t * 16 + 0) | halfbits;
            unsigned p1 = (__float_as_uint(acc[1]) & 0xFFFFFE00u) | (unsigned)(t * 16 + 1) | halfbits;
            unsigned p2 = (__float_as_uint(acc[2]) & 0xFFFFFE00u) | (unsigned)(t * 16 + 2) | halfbits;
            unsigned p3 = (__float_as_uint(acc[3]) & 0xFFFFFE00u) | (unsigned)(t * 16 + 3) | halfbits;
            unsigned a = p0 < p1 ? p0 : p1;
            unsigned b = p2 < p3 ? p2 : p3;
            unsigned m = a < b ? a : b;
            *us[c] = (*us[c] < m) ? *us[c] : m;
        }
    }

    // ---- reduce across the 4 halves sharing a column; decode k, loss -------
    float lossAcc = 0.f;
    int bks[2];
    unsigned uc[2] = {u0, u1};
    #pragma unroll
    for (int c = 0; c < 2; ++c) {
        unsigned v = uc[c];
        unsigned w16 = (unsigned)__shfl_xor((int)v, 16); v = v < w16 ? v : w16;
        unsigned w32 = (unsigned)__shfl_xor((int)v, 32); v = v < w32 ? v : w32;
        float xnf = xn[c];
        xnf += __shfl_xor(xnf, 16);
        xnf += __shfl_xor(xnf, 32);
        bks[c] = (int)(v & 511u);
        float sstar = __uint_as_float(v & 0xFFFFFE00u);   // = 1 + 0.5||q||^2 - x.q
        // ||x-q||^2 = ||x||^2 + 2*(sstar - 1); 4 lanes duplicate -> *0.25
        lossAcc += 0.25f * (xnf + 2.f * (sstar - 1.f));
    }

    // ---- coalesced gather + store: instr j writes 1KB contiguous -----------
    float* outw = out + (size_t)wrow * DIM;
    #pragma unroll
    for (int j = 0; j < 8; ++j) {
        int srcl = (j * 4 + half) & 15;
        int bk   = __shfl(bks[j >> 2], srcl);
        float4 q = *(const float4*)(cb + (size_t)bk * DIM + (lane & 15) * 4);
        *(float4*)(outw + j * 256 + lane * 4) = q;
    }

    // ---- loss partial: wave shfl-reduce, then wave0 over 16 ----------------
    #pragma unroll
    for (int off = 1; off < 64; off <<= 1) lossAcc += __shfl_xor(lossAcc, off);
    if (lane == 0) red_sh[wave] = lossAcc;
    __syncthreads();
    if (tid < 64) {
        float v = (lane < 16) ? red_sh[lane] : 0.f;
        #pragma unroll
        for (int off = 1; off < 16; off <<= 1) v += __shfl_xor(v, off);
        if (tid == 0) partials[blockIdx.x] = v;
    }
}

// ---- kernel 2: final loss reduction ----------------------------------------
__global__ void vq_finalize(const float* __restrict__ partials,
                            float* __restrict__ out_loss) {
    __shared__ float sh[256];
    int t = threadIdx.x;
    sh[t] = partials[t] + partials[t + 256];
    __syncthreads();
    #pragma unroll
    for (int s = 128; s > 0; s >>= 1) {
        if (t < s) sh[t] += sh[t + s];
        __syncthreads();
    }
    // vq_loss = 0.25*mean + mean = 1.25 * sum / (N*D)
    if (t == 0) out_loss[0] = sh[0] * (1.25f / (float)(N_ROWS * DIM));
}

extern "C" void kernel_launch(void* const* d_in, const int* in_sizes, int n_in,
                              void* d_out, int out_size, void* d_ws, size_t ws_size,
                              hipStream_t stream) {
    const float* x  = (const float*)d_in[0];
    const float* cb = (const float*)d_in[1];
    float* out      = (float*)d_out;
    float* partials = (float*)d_ws;        // BLOCKS floats

    hipLaunchKernelGGL(vq_main, dim3(BLOCKS), dim3(THREADS), 0, stream,
                       x, cb, out, partials);
    hipLaunchKernelGGL(vq_finalize, dim3(1), dim3(256), 0, stream,
                       partials, out + (size_t)N_ROWS * DIM);
}